// Round 10
// baseline (2178.657 us; speedup 1.0000x reference)
//
#include <hip/hip_runtime.h>

#define GRID    256
#define BLOCK   512
#define NWAVES  (BLOCK / 64)
#define CHUNK   7844   // ceil(2e6/255); blocks 1..255 hold the verts; leader holds 0

typedef unsigned long long u64;

// ---------------- fence-free tagged publish (cross-XCD safe) ----------------
// Relaxed agent-scope atomics on gfx950 = global_load/store ... sc0 sc1:
// bypass caches, hit the coherence point, no maintenance ops.
// Protocol history (per-step): grid.sync 28.5us (r2); acquire polls 33us (r3);
// release-fence 12.7us (r4); fence-free tagged words 9.7us (r5); SoA
// all-to-all 8.4us (r6); leader+broadcast 6.05us (r8); r9's all-wave
// receive REGRESSED to 7.3us (8x poll-wave storm on the state lines).
// r10: one global poller wave per block + LDS-flag handoffs (no barriers),
// leader owns no vertices (minimal serial chain).
__device__ __forceinline__ u64 rec_load(const u64* p) {
  return __hip_atomic_load(p, __ATOMIC_RELAXED, __HIP_MEMORY_SCOPE_AGENT);
}
__device__ __forceinline__ void rec_store(u64* p, u64 v) {
  __hip_atomic_store(p, v, __ATOMIC_RELAXED, __HIP_MEMORY_SCOPE_AGENT);
}
__device__ __forceinline__ u64 rec_pack(float f, unsigned tag) {
  return (u64)__float_as_uint(f) | ((u64)tag << 32);
}
// LDS flag handoff (workgroup scope: no cache ops, just lgkmcnt ordering)
__device__ __forceinline__ void lds_flag_set(unsigned* p, unsigned v) {
  __hip_atomic_store(p, v, __ATOMIC_RELEASE, __HIP_MEMORY_SCOPE_WORKGROUP);
}
__device__ __forceinline__ unsigned lds_flag_get(const unsigned* p) {
  return __hip_atomic_load(p, __ATOMIC_ACQUIRE, __HIP_MEMORY_SCOPE_WORKGROUP);
}

// ---------------- block reduction helper (one-time phases only) ----------------
template <int NV>
__device__ __forceinline__ void block_reduce(float* v, float* sm) {
  #pragma unroll
  for (int off = 32; off > 0; off >>= 1) {
    #pragma unroll
    for (int k = 0; k < NV; ++k) v[k] += __shfl_down(v[k], off, 64);
  }
  const int lane = threadIdx.x & 63;
  const int wid  = threadIdx.x >> 6;
  if (lane == 0) {
    #pragma unroll
    for (int k = 0; k < NV; ++k) sm[wid * NV + k] = v[k];
  }
  __syncthreads();
  if (threadIdx.x == 0) {
    #pragma unroll
    for (int w = 1; w < NWAVES; ++w) {
      #pragma unroll
      for (int k = 0; k < NV; ++k) v[k] += sm[w * NV + k];
    }
  }
  __syncthreads();
}

// ---------------- 3x3 helpers (row-major float[9]) ----------------
__device__ __forceinline__ void mat3_mul(const float* A, const float* B, float* C) {
  #pragma unroll
  for (int i = 0; i < 3; ++i)
    #pragma unroll
    for (int j = 0; j < 3; ++j)
      C[i*3+j] = A[i*3+0]*B[0*3+j] + A[i*3+1]*B[1*3+j] + A[i*3+2]*B[2*3+j];
}
__device__ __forceinline__ void mat3_mul_bt(const float* A, const float* B, float* C) {
  #pragma unroll
  for (int i = 0; i < 3; ++i)
    #pragma unroll
    for (int j = 0; j < 3; ++j)
      C[i*3+j] = A[i*3+0]*B[j*3+0] + A[i*3+1]*B[j*3+1] + A[i*3+2]*B[j*3+2];
}
__device__ __forceinline__ void mat3_inv(const float* m, float* inv) {
  float A =  (m[4]*m[8] - m[5]*m[7]);
  float B = -(m[3]*m[8] - m[5]*m[6]);
  float C =  (m[3]*m[7] - m[4]*m[6]);
  float det = m[0]*A + m[1]*B + m[2]*C;
  float id = 1.0f / det;
  inv[0] = A * id;
  inv[1] = -(m[1]*m[8] - m[2]*m[7]) * id;
  inv[2] =  (m[1]*m[5] - m[2]*m[4]) * id;
  inv[3] = B * id;
  inv[4] =  (m[0]*m[8] - m[2]*m[6]) * id;
  inv[5] = -(m[0]*m[5] - m[2]*m[3]) * id;
  inv[6] = C * id;
  inv[7] = -(m[0]*m[7] - m[1]*m[6]) * id;
  inv[8] =  (m[0]*m[4] - m[1]*m[3]) * id;
}

__global__ __launch_bounds__(BLOCK)
void sim_kernel(const float* __restrict__ xg,
                const float* __restrict__ mc_p,
                const float* __restrict__ itr_p,
                const float* __restrict__ iq_p,
                const float* __restrict__ iv_p,
                const float* __restrict__ kn_p,
                const float* __restrict__ mu_p,
                const float* __restrict__ ldp_p,
                const float* __restrict__ adp_p,
                float* __restrict__ out,
                u64* __restrict__ ws,
                int N, int T)
{
  const int tid  = threadIdx.x;
  const int bid  = blockIdx.x;
  const int lane = tid & 63;
  const int wid  = tid >> 6;

  extern __shared__ float dyn[];
  float* sXx = dyn;
  float* sXy = dyn + CHUNK;
  float* sXz = dyn + 2 * CHUNK;
  __shared__ float s_red6[NWAVES * 6];     // one-time phases
  __shared__ float s_red4[NWAVES * 4];     // hot loop partial handoff
  __shared__ float s_plane[8];
  __shared__ unsigned s_pflag;             // plane ready tag (= t)
  __shared__ unsigned s_wflag[NWAVES];     // wave partial ready tag (= t+1)

  // fp32 constants exactly as the fp32 reference sees them
  const float nx  = (float)(-0.3420201433256687);   // -sin(20deg)
  const float ny  = (float)( 0.9396926207859084);   //  cos(20deg)
  const float DTF = (float)(1.0 / 60.0 / 10.0);
  const float HDT = (float)(0.5 * (1.0 / 60.0 / 10.0));
  const float DTH = (float)(-0.9396926207859084 * 0.1); // -COS_S*INIT_HEIGHT
  const float GYDT = -9.8f * (float)(1.0 / 60.0 / 10.0);

  const float mc0 = mc_p[0], mc1 = mc_p[1], mc2 = mc_p[2];

  // workspace (u64), tagged words; ws re-poisoned 0xAA each launch -> no
  // stale-tag hazard:
  u64* part0 = ws;            // 4*GRID comp-major: word c*GRID+b (even steps)
  u64* part1 = ws + 1024;     // odd steps
  u64* st    = ws + 2048;     // 2 slots * 8 replicas * 8 words
  u64* bufI  = ws + 2176;     // 6*GRID inertia partials (slot 0 unused)

  // init LDS flags (stale LDS could alias small tags)
  if (tid == 0) s_pflag = 0;
  if (tid < NWAVES) s_wflag[tid] = 0;

  // vertex ownership: blocks 1..255 carry CHUNK each; leader carries none
  const int vstart = (bid - 1) * CHUNK;
  int cl = 0;
  if (bid > 0) { cl = N - vstart; if (cl > CHUNK) cl = CHUNK; if (cl < 0) cl = 0; }

  for (int i = tid; i < cl; i += BLOCK) {
    const float* p = xg + (size_t)(vstart + i) * 3;
    sXx[i] = p[0]; sXy[i] = p[1]; sXz[i] = p[2];
  }
  __syncthreads();   // also publishes the flag init

  // ---- inertia partial (one-time; non-leaders only have verts) ----
  if (bid > 0) {
    float v6[6] = {0,0,0,0,0,0};
    for (int i = tid; i < cl; i += BLOCK) {
      float r0 = sXx[i] - mc0, r1 = sXy[i] - mc1, r2 = sXz[i] - mc2;
      v6[0] += r0*r0; v6[1] += r1*r1; v6[2] += r2*r2;
      v6[3] += r0*r1; v6[4] += r0*r2; v6[5] += r1*r2;
    }
    block_reduce<6>(v6, s_red6);
    if (tid == 0) {
      #pragma unroll
      for (int k = 0; k < 6; ++k) rec_store(bufI + k * GRID + bid, rec_pack(v6[k], 0xC0FFEEu));
    }
  }

  // ---- leader gathers inertia (slot 0 = exact zero) ----
  float In[9];
  if (bid == 0) {
    float v6[6] = {0,0,0,0,0,0};
    if (tid > 0 && tid < GRID) {
      u64 r[6];
      int f = 0;
      for (;;) {
        #pragma unroll
        for (int k = 0; k < 6; ++k) r[k] = rec_load(bufI + k * GRID + tid);
        bool ok = true;
        #pragma unroll
        for (int k = 0; k < 6; ++k) ok &= ((unsigned)(r[k] >> 32) == 0xC0FFEEu);
        if (ok) break;
        if ((++f & 15) == 0) __builtin_amdgcn_s_sleep(1);
      }
      #pragma unroll
      for (int k = 0; k < 6; ++k) v6[k] = __uint_as_float((unsigned)r[k]);
    }
    block_reduce<6>(v6, s_red6);
    float trc = v6[0] + v6[1] + v6[2];
    In[0] = trc - v6[0]; In[4] = trc - v6[1]; In[8] = trc - v6[2];
    In[1] = -v6[3]; In[3] = -v6[3];
    In[2] = -v6[4]; In[6] = -v6[4];
    In[5] = -v6[5]; In[7] = -v6[5];
  }

  // ---- initial state ----
  float tr0 = itr_p[0], tr1 = itr_p[1], tr2 = itr_p[2];
  float q0 = iq_p[0], q1 = iq_p[1], q2 = iq_p[2], q3 = iq_p[3];
  {
    float n0 = sqrtf(q0*q0 + q1*q1 + q2*q2 + q3*q3);
    q0 /= n0; q1 /= n0; q2 /= n0; q3 /= n0;
  }
  float v0 = iv_p[0], v1 = iv_p[1], v2 = iv_p[2];
  float om0 = 0.f, om1 = 0.f, om2 = 0.f;
  const float knv = kn_p[0], muv = mu_p[0], ldv = ldp_p[0], adv = adp_p[0];
  const float inv_mass = 1.0f / (float)N;

  if (bid == 0) {
    // =================== LEADER: no verts, minimal serial chain ===================
    float Rm[9], Ii[9];
    if (tid == 0) {
      float qn = sqrtf(q0*q0 + q1*q1 + q2*q2 + q3*q3);
      float w = q0/qn, xq = q1/qn, yq = q2/qn, zq = q3/qn;
      Rm[0] = 1.f - 2.f*yq*yq - 2.f*zq*zq; Rm[1] = 2.f*xq*yq - 2.f*w*zq; Rm[2] = 2.f*xq*zq + 2.f*w*yq;
      Rm[3] = 2.f*xq*yq + 2.f*w*zq; Rm[4] = 1.f - 2.f*xq*xq - 2.f*zq*zq; Rm[5] = 2.f*yq*zq - 2.f*w*xq;
      Rm[6] = 2.f*xq*zq - 2.f*w*yq; Rm[7] = 2.f*yq*zq + 2.f*w*xq; Rm[8] = 1.f - 2.f*xq*xq - 2.f*yq*yq;
      float Tm[9]; mat3_mul(Rm, In, Tm);
      float Iw[9]; mat3_mul_bt(Tm, Rm, Iw);
      mat3_inv(Iw, Ii);
    }
    const bool skipLane = ((tid & 255) == 0);   // block-0 words (never written)
    for (int t = 0; t < T; ++t) {
      const unsigned want = (unsigned)(t + 1);
      u64* pb = (t & 1) ? part1 : part0;
      // 8 waves spin-gather 255 partials (comp-major, coalesced)
      u64 wA = 0, wB = 0;
      {
        int f = 0;
        for (;;) {
          if (!skipLane) { wA = rec_load(pb + tid); wB = rec_load(pb + 512 + tid); }
          bool ok = skipLane || (((unsigned)(wA >> 32) == want) &&
                                 ((unsigned)(wB >> 32) == want));
          if (__ballot(ok) == ~0ull) break;
          if ((++f & 15) == 0) __builtin_amdgcn_s_sleep(1);
        }
      }
      float pA = skipLane ? 0.f : __uint_as_float((unsigned)wA);
      float pB = skipLane ? 0.f : __uint_as_float((unsigned)wB);
      #pragma unroll
      for (int off = 32; off > 0; off >>= 1) {
        pA += __shfl_down(pA, off, 64);
        pB += __shfl_down(pB, off, 64);
      }
      if (lane == 0) {
        s_red4[wid * 2] = pA; s_red4[wid * 2 + 1] = pB;
        lds_flag_set(&s_wflag[wid], want);
      }
      if (tid == 0) {
        #pragma unroll
        for (int w2 = 1; w2 < NWAVES; ++w2) {
          int f = 0;
          while (lds_flag_get(&s_wflag[w2]) != want)
            if ((++f & 31) == 0) __builtin_amdgcn_s_sleep(1);
        }
        // waves 0-3 hold comps 0(A)/2(B); waves 4-7 hold comps 1/3
        float tot0 = s_red4[0] + s_red4[2]  + s_red4[4]  + s_red4[6];
        float tot2 = s_red4[1] + s_red4[3]  + s_red4[5]  + s_red4[7];
        float tot1 = s_red4[8] + s_red4[10] + s_red4[12] + s_red4[14];
        float tot3 = s_red4[9] + s_red4[11] + s_red4[13] + s_red4[15];

        float num = tot0;
        float numf = fmaxf(num, 1.0f);
        float ri0 = tot1 / numf, ri1 = tot2 / numf, ri2 = tot3 / numf;
        float Ri0 = Rm[0]*ri0 + Rm[1]*ri1 + Rm[2]*ri2;
        float Ri1 = Rm[3]*ri0 + Rm[4]*ri1 + Rm[5]*ri2;
        float Ri2 = Rm[6]*ri0 + Rm[7]*ri1 + Rm[8]*ri2;
        float dv0 = 0.f, dv1 = 0.f, dv2 = 0.f, dm0 = 0.f, dm1 = 0.f, dm2 = 0.f;
        if (num > 0.0f) {
          float vi0 = v0 + om1*Ri2 - om2*Ri1;
          float vi1 = v1 + om2*Ri0 - om0*Ri2;
          float vi2 = v2 + om0*Ri1 - om1*Ri0;
          float vdn = vi0*nx + vi1*ny;
          float vn0 = vdn*nx, vn1 = vdn*ny;           // vn2 == 0 exactly
          float vt0 = vi0 - vn0, vt1 = vi1 - vn1, vt2 = vi2;
          float nvn = sqrtf(vn0*vn0 + vn1*vn1);
          float nvt = sqrtf(vt0*vt0 + vt1*vt1 + vt2*vt2);
          float alpha = fmaxf(1.0f - muv*(1.0f + knv)*(nvn/(nvt + 1e-6f)), 0.0f);
          float dvi0 = (-knv*vn0 + alpha*vt0) - vi0;
          float dvi1 = (-knv*vn1 + alpha*vt1) - vi1;
          float dvi2 = (alpha*vt2) - vi2;
          float Cx[9] = {0.f, -Ri2, Ri1,  Ri2, 0.f, -Ri0,  -Ri1, Ri0, 0.f};
          float T2[9]; mat3_mul(Cx, Ii, T2);
          float T3[9]; mat3_mul(T2, Cx, T3);
          float K[9];
          #pragma unroll
          for (int k = 0; k < 9; ++k) K[k] = -T3[k];
          K[0] += inv_mass; K[4] += inv_mass; K[8] += inv_mass;
          float Ki[9]; mat3_inv(K, Ki);
          float J0 = Ki[0]*dvi0 + Ki[1]*dvi1 + Ki[2]*dvi2;
          float J1 = Ki[3]*dvi0 + Ki[4]*dvi1 + Ki[5]*dvi2;
          float J2 = Ki[6]*dvi0 + Ki[7]*dvi1 + Ki[8]*dvi2;
          dv0 = J0*inv_mass; dv1 = J1*inv_mass; dv2 = J2*inv_mass;
          float c0 = -Ri2*J1 + Ri1*J2;
          float c1 =  Ri2*J0 - Ri0*J2;
          float c2 = -Ri1*J0 + Ri0*J1;
          dm0 = Ii[0]*c0 + Ii[1]*c1 + Ii[2]*c2;
          dm1 = Ii[3]*c0 + Ii[4]*c1 + Ii[5]*c2;
          dm2 = Ii[6]*c0 + Ii[7]*c1 + Ii[8]*c2;
        }
        v0 = v0*ldv + dv0;
        v1 = (v1 + GYDT)*ldv + dv1;
        v2 = v2*ldv + dv2;
        om0 = om0*adv + dm0; om1 = om1*adv + dm1; om2 = om2*adv + dm2;
        tr0 = tr0 + DTF*v0; tr1 = tr1 + DTF*v1; tr2 = tr2 + DTF*v2;
        float wx = om0*HDT, wy = om1*HDT, wz = om2*HDT;
        float dq0 = -wx*q1 - wy*q2 - wz*q3;
        float dq1 =  wx*q0 + wy*q3 - wz*q2;
        float dq2 =  wy*q0 + wz*q1 - wx*q3;
        float dq3 =  wz*q0 + wx*q2 - wy*q1;
        q0 += dq0; q1 += dq1; q2 += dq2; q3 += dq3;
        float qn2 = sqrtf(q0*q0 + q1*q1 + q2*q2 + q3*q3);
        q0 /= qn2; q1 /= qn2; q2 /= qn2; q3 /= qn2;

        // next plane params
        float qn = sqrtf(q0*q0 + q1*q1 + q2*q2 + q3*q3);
        float w = q0/qn, xq = q1/qn, yq = q2/qn, zq = q3/qn;
        Rm[0] = 1.f - 2.f*yq*yq - 2.f*zq*zq; Rm[1] = 2.f*xq*yq - 2.f*w*zq; Rm[2] = 2.f*xq*zq + 2.f*w*yq;
        Rm[3] = 2.f*xq*yq + 2.f*w*zq; Rm[4] = 1.f - 2.f*xq*xq - 2.f*zq*zq; Rm[5] = 2.f*yq*zq - 2.f*w*xq;
        Rm[6] = 2.f*xq*zq - 2.f*w*yq; Rm[7] = 2.f*yq*zq + 2.f*w*xq; Rm[8] = 1.f - 2.f*xq*xq - 2.f*yq*yq;
        float pl[8];
        pl[0] = Rm[0]*nx + Rm[3]*ny;
        pl[1] = Rm[1]*nx + Rm[4]*ny;
        pl[2] = Rm[2]*nx + Rm[5]*ny;
        float w0 = ny*om2, w1 = -nx*om2, w2 = nx*om1 - ny*om0;
        pl[3] = Rm[0]*w0 + Rm[3]*w1 + Rm[6]*w2;
        pl[4] = Rm[1]*w0 + Rm[4]*w1 + Rm[7]*w2;
        pl[5] = Rm[2]*w0 + Rm[5]*w1 + Rm[8]*w2;
        pl[6] = DTH - ((tr0 + mc0)*nx + (tr1 + mc1)*ny);
        pl[7] = -(v0*nx + v1*ny);

        // broadcast FIRST (critical path): 8 replicas x 8 words
        u64* sl = st + (size_t)((t + 1) & 1) * 64;
        #pragma unroll
        for (int r = 0; r < 8; ++r) {
          #pragma unroll
          for (int k = 0; k < 8; ++k) rec_store(sl + r * 8 + k, rec_pack(pl[k], want));
        }
        // off critical path: output + hoist next inertia inversion
        float* o = out + (size_t)t * 7;
        o[0] = tr0; o[1] = tr1; o[2] = tr2;
        o[3] = q0;  o[4] = q1;  o[5] = q2;  o[6] = q3;
        float Tm[9]; mat3_mul(Rm, In, Tm);
        float Iw[9]; mat3_mul_bt(Tm, Rm, Iw);
        mat3_inv(Iw, Ii);
      }
    }
  } else {
    // =================== NON-LEADER: scan + publish, zero barriers ===================
    const int rep = bid & 7;
    float a0, a1, a2, b0, b1, b2, ca, cb;
    {
      // P_0 locally (identical fp ops everywhere)
      float qn = sqrtf(q0*q0 + q1*q1 + q2*q2 + q3*q3);
      float w = q0/qn, xq = q1/qn, yq = q2/qn, zq = q3/qn;
      float R0 = 1.f - 2.f*yq*yq - 2.f*zq*zq, R1 = 2.f*xq*yq - 2.f*w*zq, R2 = 2.f*xq*zq + 2.f*w*yq;
      float R3 = 2.f*xq*yq + 2.f*w*zq, R4 = 1.f - 2.f*xq*xq - 2.f*zq*zq, R5 = 2.f*yq*zq - 2.f*w*xq;
      float R6 = 2.f*xq*zq - 2.f*w*yq, R7 = 2.f*yq*zq + 2.f*w*xq, R8 = 1.f - 2.f*xq*xq - 2.f*yq*yq;
      a0 = R0*nx + R3*ny; a1 = R1*nx + R4*ny; a2 = R2*nx + R5*ny;
      float w0 = ny*om2, w1 = -nx*om2, w2 = nx*om1 - ny*om0;   // = 0 exactly
      b0 = R0*w0 + R3*w1 + R6*w2;
      b1 = R1*w0 + R4*w1 + R7*w2;
      b2 = R2*w0 + R5*w1 + R8*w2;
      ca = DTH - ((tr0 + mc0)*nx + (tr1 + mc1)*ny);
      cb = -(v0*nx + v1*ny);
    }
    for (int t = 0; t < T; ++t) {
      if (t > 0) {
        if (wid == 0) {
          // ONE polling wave per block (r8 level of global poll traffic)
          const u64* sl = st + (size_t)(t & 1) * 64 + (size_t)rep * 8;
          u64 v;
          int f = 0;
          for (;;) {
            v = rec_load(sl + (lane & 7));
            bool ok = ((unsigned)(v >> 32) == (unsigned)t);
            unsigned long long m = __ballot(ok);
            if ((m & 0xFFull) == 0xFFull) break;
            if ((++f & 7) == 0) __builtin_amdgcn_s_sleep(1);
          }
          float fv = __uint_as_float((unsigned)v);
          a0 = __shfl(fv, 0, 64); a1 = __shfl(fv, 1, 64); a2 = __shfl(fv, 2, 64);
          b0 = __shfl(fv, 3, 64); b1 = __shfl(fv, 4, 64); b2 = __shfl(fv, 5, 64);
          ca = __shfl(fv, 6, 64); cb = __shfl(fv, 7, 64);
          if (lane < 8) s_plane[lane] = fv;
          if (lane == 0) lds_flag_set(&s_pflag, (unsigned)t);  // lgkmcnt(0) covers wave's ds_writes
        } else {
          // other waves spin on the on-chip flag (no global traffic, no barrier)
          int f = 0;
          while (lds_flag_get(&s_pflag) != (unsigned)t)
            if ((++f & 31) == 0) __builtin_amdgcn_s_sleep(1);
          a0 = s_plane[0]; a1 = s_plane[1]; a2 = s_plane[2];
          b0 = s_plane[3]; b1 = s_plane[4]; b2 = s_plane[5];
          ca = s_plane[6]; cb = s_plane[7];
        }
      }

      float acc[4] = {0.f, 0.f, 0.f, 0.f};
      for (int i = tid; i < cl; i += BLOCK) {
        float x0 = sXx[i], x1 = sXy[i], x2 = sXz[i];
        float da = x0*a0 + x1*a1 + x2*a2;
        float db = x0*b0 + x1*b1 + x2*b2;
        if (da < ca && db < cb) { acc[0] += 1.f; acc[1] += x0; acc[2] += x1; acc[3] += x2; }
      }
      #pragma unroll
      for (int off = 32; off > 0; off >>= 1) {
        #pragma unroll
        for (int k = 0; k < 4; ++k) acc[k] += __shfl_down(acc[k], off, 64);
      }
      const unsigned want = (unsigned)(t + 1);
      if (lane == 0) {
        #pragma unroll
        for (int k = 0; k < 4; ++k) s_red4[wid * 4 + k] = acc[k];
        lds_flag_set(&s_wflag[wid], want);
      }
      if (tid == 0) {
        #pragma unroll
        for (int w2 = 1; w2 < NWAVES; ++w2) {
          int f = 0;
          while (lds_flag_get(&s_wflag[w2]) != want)
            if ((++f & 31) == 0) __builtin_amdgcn_s_sleep(1);
        }
        #pragma unroll
        for (int w2 = 1; w2 < NWAVES; ++w2) {
          #pragma unroll
          for (int k = 0; k < 4; ++k) acc[k] += s_red4[w2 * 4 + k];
        }
        u64* pb = (t & 1) ? part1 : part0;
        #pragma unroll
        for (int k = 0; k < 4; ++k) rec_store(pb + k * GRID + bid, rec_pack(acc[k], want));
      }
      // WAR safety (s_plane, s_red4, global part buffers): a wave reaches its
      // step-(t+1) writes only after plane t+1 arrived, which the leader sends
      // only after consuming this block's step-t partial -> all step-t reads
      // happened-before any step-(t+1) overwrite.
    }
  }
}

extern "C" void kernel_launch(void* const* d_in, const int* in_sizes, int n_in,
                              void* d_out, int out_size, void* d_ws, size_t ws_size,
                              hipStream_t stream) {
  const float* x   = (const float*)d_in[0];
  const float* mc  = (const float*)d_in[1];
  const float* itr = (const float*)d_in[2];
  const float* iq  = (const float*)d_in[3];
  const float* iv  = (const float*)d_in[4];
  const float* kn  = (const float*)d_in[5];
  const float* mu  = (const float*)d_in[6];
  const float* ldp = (const float*)d_in[7];
  const float* adp = (const float*)d_in[8];
  float* out = (float*)d_out;
  u64* ws  = (u64*)d_ws;
  int N = in_sizes[0] / 3;
  int T = out_size / 7;

  const int dyn_lds = 3 * CHUNK * 4;   // 94128 B < 160 KB/CU
  hipFuncSetAttribute((const void*)sim_kernel,
                      hipFuncAttributeMaxDynamicSharedMemorySize, dyn_lds);

  void* args[] = {(void*)&x, (void*)&mc, (void*)&itr, (void*)&iq, (void*)&iv,
                  (void*)&kn, (void*)&mu, (void*)&ldp, (void*)&adp,
                  (void*)&out, (void*)&ws, (void*)&N, (void*)&T};
  // cooperative launch kept ONLY for the co-residency guarantee (no grid.sync inside)
  hipLaunchCooperativeKernel((void*)sim_kernel, dim3(GRID), dim3(BLOCK),
                             args, dyn_lds, stream);
}

// Round 11
// 1613.543 us; speedup vs baseline: 1.3502x; 1.3502x over previous
//
#include <hip/hip_runtime.h>

#define GRID    256
#define BLOCK   512
#define NWAVES  (BLOCK / 64)
#define CHUNK   7813    // ceil(2e6/256) verts per block
#define CHUNKP  7816    // padded to mult of 4 for float4 LDS reads

typedef unsigned long long u64;

// ---------------- fence-free tagged publish (cross-XCD safe) ----------------
// Relaxed agent-scope atomics on gfx950 = global_load/store ... sc0 sc1:
// bypass caches, hit the coherence point, no maintenance ops.
// Per-step protocol history: grid.sync 28.5us (r2); acquire polls 33us (r3);
// release-fence 12.7us (r4); fence-free tagged words 9.7us (r5); SoA
// all-to-all 8.4us (r6); leader+broadcast+barrier-handoff 6.05us (r8).
// r9 (all-wave receive: poll storm) and r10 (LDS-flag spins, slower than
// s_barrier) both REGRESSED -> r11 = r8 verbatim + hoisted inertia
// inversion + broadcast-first (both r9-verified bit-exact) + float4 scan.
__device__ __forceinline__ u64 rec_load(const u64* p) {
  return __hip_atomic_load(p, __ATOMIC_RELAXED, __HIP_MEMORY_SCOPE_AGENT);
}
__device__ __forceinline__ void rec_store(u64* p, u64 v) {
  __hip_atomic_store(p, v, __ATOMIC_RELAXED, __HIP_MEMORY_SCOPE_AGENT);
}
__device__ __forceinline__ u64 rec_pack(float f, unsigned tag) {
  return (u64)__float_as_uint(f) | ((u64)tag << 32);
}

// ---------------- block reduction helper (one-time phases only) ----------------
template <int NV>
__device__ __forceinline__ void block_reduce(float* v, float* sm) {
  #pragma unroll
  for (int off = 32; off > 0; off >>= 1) {
    #pragma unroll
    for (int k = 0; k < NV; ++k) v[k] += __shfl_down(v[k], off, 64);
  }
  const int lane = threadIdx.x & 63;
  const int wid  = threadIdx.x >> 6;
  if (lane == 0) {
    #pragma unroll
    for (int k = 0; k < NV; ++k) sm[wid * NV + k] = v[k];
  }
  __syncthreads();
  if (threadIdx.x == 0) {
    #pragma unroll
    for (int w = 1; w < NWAVES; ++w) {
      #pragma unroll
      for (int k = 0; k < NV; ++k) v[k] += sm[w * NV + k];
    }
  }
  __syncthreads();
}

// ---------------- 3x3 helpers (row-major float[9]) ----------------
__device__ __forceinline__ void mat3_mul(const float* A, const float* B, float* C) {
  #pragma unroll
  for (int i = 0; i < 3; ++i)
    #pragma unroll
    for (int j = 0; j < 3; ++j)
      C[i*3+j] = A[i*3+0]*B[0*3+j] + A[i*3+1]*B[1*3+j] + A[i*3+2]*B[2*3+j];
}
__device__ __forceinline__ void mat3_mul_bt(const float* A, const float* B, float* C) {
  #pragma unroll
  for (int i = 0; i < 3; ++i)
    #pragma unroll
    for (int j = 0; j < 3; ++j)
      C[i*3+j] = A[i*3+0]*B[j*3+0] + A[i*3+1]*B[j*3+1] + A[i*3+2]*B[j*3+2];
}
__device__ __forceinline__ void mat3_inv(const float* m, float* inv) {
  float A =  (m[4]*m[8] - m[5]*m[7]);
  float B = -(m[3]*m[8] - m[5]*m[6]);
  float C =  (m[3]*m[7] - m[4]*m[6]);
  float det = m[0]*A + m[1]*B + m[2]*C;
  float id = 1.0f / det;
  inv[0] = A * id;
  inv[1] = -(m[1]*m[8] - m[2]*m[7]) * id;
  inv[2] =  (m[1]*m[5] - m[2]*m[4]) * id;
  inv[3] = B * id;
  inv[4] =  (m[0]*m[8] - m[2]*m[6]) * id;
  inv[5] = -(m[0]*m[5] - m[2]*m[3]) * id;
  inv[6] = C * id;
  inv[7] = -(m[0]*m[7] - m[1]*m[6]) * id;
  inv[8] =  (m[0]*m[4] - m[1]*m[3]) * id;
}

__global__ __launch_bounds__(BLOCK)
void sim_kernel(const float* __restrict__ xg,
                const float* __restrict__ mc_p,
                const float* __restrict__ itr_p,
                const float* __restrict__ iq_p,
                const float* __restrict__ iv_p,
                const float* __restrict__ kn_p,
                const float* __restrict__ mu_p,
                const float* __restrict__ ldp_p,
                const float* __restrict__ adp_p,
                float* __restrict__ out,
                u64* __restrict__ ws,
                int N, int T)
{
  const int tid  = threadIdx.x;
  const int bid  = blockIdx.x;
  const int lane = tid & 63;
  const int wid  = tid >> 6;

  extern __shared__ float dyn[];
  float* sXx = dyn;
  float* sXy = dyn + CHUNKP;
  float* sXz = dyn + 2 * CHUNKP;
  __shared__ float s_red6[NWAVES * 6];   // one-time phases
  __shared__ float s_red4[NWAVES * 4];   // hot loop: block partial
  __shared__ float s_red2[NWAVES * 2];   // hot loop: leader gather
  __shared__ float s_plane[8];

  // fp32 constants exactly as the fp32 reference sees them
  const float nx  = (float)(-0.3420201433256687);   // -sin(20deg)
  const float ny  = (float)( 0.9396926207859084);   //  cos(20deg)
  const float DTF = (float)(1.0 / 60.0 / 10.0);
  const float HDT = (float)(0.5 * (1.0 / 60.0 / 10.0));
  const float DTH = (float)(-0.9396926207859084 * 0.1); // -COS_S*INIT_HEIGHT
  const float GYDT = -9.8f * (float)(1.0 / 60.0 / 10.0);

  const float mc0 = mc_p[0], mc1 = mc_p[1], mc2 = mc_p[2];

  // workspace (u64), tagged words; poison 0xAAAAAAAA != any tag (1..240, 0xC0FFEE)
  u64* part0 = ws;            // 4*GRID comp-major: word c*GRID+b (even steps)
  u64* part1 = ws + 1024;     // odd steps
  u64* st    = ws + 2048;     // 2 slots * 8 replicas * 8 words
  u64* bufI  = ws + 2176;     // 6*GRID inertia partials

  const int vstart = bid * CHUNK;
  int cl = N - vstart; if (cl > CHUNK) cl = CHUNK; if (cl < 0) cl = 0;

  // ---- stage this block's slice of x into LDS (SoA) ----
  for (int i = tid; i < cl; i += BLOCK) {
    const float* p = xg + (size_t)(vstart + i) * 3;
    sXx[i] = p[0]; sXy[i] = p[1]; sXz[i] = p[2];
  }
  __syncthreads();

  // ---- inertia partial over this slice (one-time; r8 order -> bit-exact In) ----
  {
    float v6[6] = {0,0,0,0,0,0};
    for (int i = tid; i < cl; i += BLOCK) {
      float r0 = sXx[i] - mc0, r1 = sXy[i] - mc1, r2 = sXz[i] - mc2;
      v6[0] += r0*r0; v6[1] += r1*r1; v6[2] += r2*r2;
      v6[3] += r0*r1; v6[4] += r0*r2; v6[5] += r1*r2;
    }
    block_reduce<6>(v6, s_red6);
    if (tid == 0) {
      #pragma unroll
      for (int k = 0; k < 6; ++k) rec_store(bufI + k * GRID + bid, rec_pack(v6[k], 0xC0FFEEu));
    }
  }

  // ---- leader gathers inertia ----
  float In[9];
  if (bid == 0) {
    float v6[6] = {0,0,0,0,0,0};
    if (tid < GRID) {
      u64 r[6];
      int f = 0;
      for (;;) {
        #pragma unroll
        for (int k = 0; k < 6; ++k) r[k] = rec_load(bufI + k * GRID + tid);
        bool ok = true;
        #pragma unroll
        for (int k = 0; k < 6; ++k) ok &= ((unsigned)(r[k] >> 32) == 0xC0FFEEu);
        if (ok) break;
        if ((++f & 15) == 0) __builtin_amdgcn_s_sleep(1);
      }
      #pragma unroll
      for (int k = 0; k < 6; ++k) v6[k] = __uint_as_float((unsigned)r[k]);
    }
    block_reduce<6>(v6, s_red6);
    float trc = v6[0] + v6[1] + v6[2];
    In[0] = trc - v6[0]; In[4] = trc - v6[1]; In[8] = trc - v6[2];
    In[1] = -v6[3]; In[3] = -v6[3];
    In[2] = -v6[4]; In[6] = -v6[4];
    In[5] = -v6[5]; In[7] = -v6[5];
  }

  // ---- initial state; every thread computes identical P_0 ----
  float tr0 = itr_p[0], tr1 = itr_p[1], tr2 = itr_p[2];
  float q0 = iq_p[0], q1 = iq_p[1], q2 = iq_p[2], q3 = iq_p[3];
  {
    float n0 = sqrtf(q0*q0 + q1*q1 + q2*q2 + q3*q3);
    q0 /= n0; q1 /= n0; q2 /= n0; q3 /= n0;
  }
  float v0 = iv_p[0], v1 = iv_p[1], v2 = iv_p[2];
  float om0 = 0.f, om1 = 0.f, om2 = 0.f;
  const float knv = kn_p[0], muv = mu_p[0], ldv = ldp_p[0], adv = adp_p[0];
  const float inv_mass = 1.0f / (float)N;

  float Rm[9];     // leader thread 0 persistent
  float Ii[9];     // hoisted inv(R In R^T), leader thread 0
  float a0, a1, a2, b0, b1, b2, ca, cb;

  {
    // P_0 (all threads; identical fp ops)
    float qn = sqrtf(q0*q0 + q1*q1 + q2*q2 + q3*q3);
    float w = q0/qn, xq = q1/qn, yq = q2/qn, zq = q3/qn;
    float R0 = 1.f - 2.f*yq*yq - 2.f*zq*zq, R1 = 2.f*xq*yq - 2.f*w*zq, R2 = 2.f*xq*zq + 2.f*w*yq;
    float R3 = 2.f*xq*yq + 2.f*w*zq, R4 = 1.f - 2.f*xq*xq - 2.f*zq*zq, R5 = 2.f*yq*zq - 2.f*w*xq;
    float R6 = 2.f*xq*zq - 2.f*w*yq, R7 = 2.f*yq*zq + 2.f*w*xq, R8 = 1.f - 2.f*xq*xq - 2.f*yq*yq;
    a0 = R0*nx + R3*ny; a1 = R1*nx + R4*ny; a2 = R2*nx + R5*ny;
    float w0 = ny*om2, w1 = -nx*om2, w2 = nx*om1 - ny*om0;   // = 0 exactly
    b0 = R0*w0 + R3*w1 + R6*w2;
    b1 = R1*w0 + R4*w1 + R7*w2;
    b2 = R2*w0 + R5*w1 + R8*w2;
    ca = DTH - ((tr0 + mc0)*nx + (tr1 + mc1)*ny);
    cb = -(v0*nx + v1*ny);
    if (bid == 0 && tid == 0) {
      Rm[0]=R0; Rm[1]=R1; Rm[2]=R2; Rm[3]=R3; Rm[4]=R4; Rm[5]=R5; Rm[6]=R6; Rm[7]=R7; Rm[8]=R8;
      s_plane[0]=a0; s_plane[1]=a1; s_plane[2]=a2;
      s_plane[3]=b0; s_plane[4]=b1; s_plane[5]=b2;
      s_plane[6]=ca; s_plane[7]=cb;
      float Tm[9]; mat3_mul(Rm, In, Tm);
      float Iw[9]; mat3_mul_bt(Tm, Rm, Iw);
      mat3_inv(Iw, Ii);
    }
  }

  // float4 views for the vectorized scan (CHUNKP mult of 4, base 16B aligned)
  const float4* pX4 = (const float4*)sXx;
  const float4* pY4 = (const float4*)sXy;
  const float4* pZ4 = (const float4*)sXz;
  const int seg0 = tid * 16;
  int segEnd = seg0 + 16; if (segEnd > cl) segEnd = cl;

  if (bid == 0) {
    // =================== LEADER BLOCK ===================
    for (int t = 0; t < T; ++t) {
      __syncthreads();   // s_plane handoff from end of previous step / init
      a0 = s_plane[0]; a1 = s_plane[1]; a2 = s_plane[2];
      b0 = s_plane[3]; b1 = s_plane[4]; b2 = s_plane[5];
      ca = s_plane[6]; cb = s_plane[7];

      float acc[4] = {0.f, 0.f, 0.f, 0.f};
      int i = seg0;
      for (; i + 4 <= segEnd; i += 4) {
        float4 xx = pX4[i >> 2], yy = pY4[i >> 2], zz = pZ4[i >> 2];
        float da, db;
        da = xx.x*a0 + yy.x*a1 + zz.x*a2; db = xx.x*b0 + yy.x*b1 + zz.x*b2;
        if (da < ca && db < cb) { acc[0] += 1.f; acc[1] += xx.x; acc[2] += yy.x; acc[3] += zz.x; }
        da = xx.y*a0 + yy.y*a1 + zz.y*a2; db = xx.y*b0 + yy.y*b1 + zz.y*b2;
        if (da < ca && db < cb) { acc[0] += 1.f; acc[1] += xx.y; acc[2] += yy.y; acc[3] += zz.y; }
        da = xx.z*a0 + yy.z*a1 + zz.z*a2; db = xx.z*b0 + yy.z*b1 + zz.z*b2;
        if (da < ca && db < cb) { acc[0] += 1.f; acc[1] += xx.z; acc[2] += yy.z; acc[3] += zz.z; }
        da = xx.w*a0 + yy.w*a1 + zz.w*a2; db = xx.w*b0 + yy.w*b1 + zz.w*b2;
        if (da < ca && db < cb) { acc[0] += 1.f; acc[1] += xx.w; acc[2] += yy.w; acc[3] += zz.w; }
      }
      for (; i < segEnd; ++i) {
        float x0 = sXx[i], x1 = sXy[i], x2 = sXz[i];
        float da = x0*a0 + x1*a1 + x2*a2;
        float db = x0*b0 + x1*b1 + x2*b2;
        if (da < ca && db < cb) { acc[0] += 1.f; acc[1] += x0; acc[2] += x1; acc[3] += x2; }
      }
      #pragma unroll
      for (int off = 32; off > 0; off >>= 1) {
        #pragma unroll
        for (int k = 0; k < 4; ++k) acc[k] += __shfl_down(acc[k], off, 64);
      }
      if (lane == 0) {
        #pragma unroll
        for (int k = 0; k < 4; ++k) s_red4[wid * 4 + k] = acc[k];
      }
      __syncthreads();
      const unsigned want = (unsigned)(t + 1);
      u64* pb = (t & 1) ? part1 : part0;
      if (tid == 0) {
        #pragma unroll
        for (int w = 1; w < NWAVES; ++w) {
          #pragma unroll
          for (int k = 0; k < 4; ++k) acc[k] += s_red4[w * 4 + k];
        }
        #pragma unroll
        for (int k = 0; k < 4; ++k) rec_store(pb + k * GRID + 0, rec_pack(acc[k], want));
      }

      // per-thread spin: words tid (comps 0/1) and tid+512 (comps 2/3)
      u64 wA, wB;
      {
        int f = 0;
        for (;;) {
          wA = rec_load(pb + tid);
          wB = rec_load(pb + 512 + tid);
          if ((unsigned)(wA >> 32) == want && (unsigned)(wB >> 32) == want) break;
          if ((++f & 15) == 0) __builtin_amdgcn_s_sleep(1);
        }
      }
      float pA = __uint_as_float((unsigned)wA);
      float pB = __uint_as_float((unsigned)wB);
      #pragma unroll
      for (int off = 32; off > 0; off >>= 1) {
        pA += __shfl_down(pA, off, 64);
        pB += __shfl_down(pB, off, 64);
      }
      if (lane == 0) { s_red2[wid * 2] = pA; s_red2[wid * 2 + 1] = pB; }
      __syncthreads();

      if (tid == 0) {
        // waves 0-3: comps 0(A)/2(B); waves 4-7: comps 1/3
        float tot0 = s_red2[0] + s_red2[2]  + s_red2[4]  + s_red2[6];
        float tot2 = s_red2[1] + s_red2[3]  + s_red2[5]  + s_red2[7];
        float tot1 = s_red2[8] + s_red2[10] + s_red2[12] + s_red2[14];
        float tot3 = s_red2[9] + s_red2[11] + s_red2[13] + s_red2[15];

        float num = tot0;
        float numf = fmaxf(num, 1.0f);
        float ri0 = tot1 / numf, ri1 = tot2 / numf, ri2 = tot3 / numf;
        float Ri0 = Rm[0]*ri0 + Rm[1]*ri1 + Rm[2]*ri2;
        float Ri1 = Rm[3]*ri0 + Rm[4]*ri1 + Rm[5]*ri2;
        float Ri2 = Rm[6]*ri0 + Rm[7]*ri1 + Rm[8]*ri2;
        float dv0 = 0.f, dv1 = 0.f, dv2 = 0.f, dm0 = 0.f, dm1 = 0.f, dm2 = 0.f;
        if (num > 0.0f) {
          float vi0 = v0 + om1*Ri2 - om2*Ri1;
          float vi1 = v1 + om2*Ri0 - om0*Ri2;
          float vi2 = v2 + om0*Ri1 - om1*Ri0;
          float vdn = vi0*nx + vi1*ny;
          float vn0 = vdn*nx, vn1 = vdn*ny;           // vn2 == 0 exactly
          float vt0 = vi0 - vn0, vt1 = vi1 - vn1, vt2 = vi2;
          float nvn = sqrtf(vn0*vn0 + vn1*vn1);
          float nvt = sqrtf(vt0*vt0 + vt1*vt1 + vt2*vt2);
          float alpha = fmaxf(1.0f - muv*(1.0f + knv)*(nvn/(nvt + 1e-6f)), 0.0f);
          float dvi0 = (-knv*vn0 + alpha*vt0) - vi0;
          float dvi1 = (-knv*vn1 + alpha*vt1) - vi1;
          float dvi2 = (alpha*vt2) - vi2;
          // Ii hoisted (computed after previous broadcast)
          float Cx[9] = {0.f, -Ri2, Ri1,  Ri2, 0.f, -Ri0,  -Ri1, Ri0, 0.f};
          float T2[9]; mat3_mul(Cx, Ii, T2);
          float T3[9]; mat3_mul(T2, Cx, T3);
          float K[9];
          #pragma unroll
          for (int k = 0; k < 9; ++k) K[k] = -T3[k];
          K[0] += inv_mass; K[4] += inv_mass; K[8] += inv_mass;
          float Ki[9]; mat3_inv(K, Ki);
          float J0 = Ki[0]*dvi0 + Ki[1]*dvi1 + Ki[2]*dvi2;
          float J1 = Ki[3]*dvi0 + Ki[4]*dvi1 + Ki[5]*dvi2;
          float J2 = Ki[6]*dvi0 + Ki[7]*dvi1 + Ki[8]*dvi2;
          dv0 = J0*inv_mass; dv1 = J1*inv_mass; dv2 = J2*inv_mass;
          float c0 = -Ri2*J1 + Ri1*J2;
          float c1 =  Ri2*J0 - Ri0*J2;
          float c2 = -Ri1*J0 + Ri0*J1;
          dm0 = Ii[0]*c0 + Ii[1]*c1 + Ii[2]*c2;
          dm1 = Ii[3]*c0 + Ii[4]*c1 + Ii[5]*c2;
          dm2 = Ii[6]*c0 + Ii[7]*c1 + Ii[8]*c2;
        }
        v0 = v0*ldv + dv0;
        v1 = (v1 + GYDT)*ldv + dv1;
        v2 = v2*ldv + dv2;
        om0 = om0*adv + dm0; om1 = om1*adv + dm1; om2 = om2*adv + dm2;
        tr0 = tr0 + DTF*v0; tr1 = tr1 + DTF*v1; tr2 = tr2 + DTF*v2;
        float wx = om0*HDT, wy = om1*HDT, wz = om2*HDT;
        float dq0 = -wx*q1 - wy*q2 - wz*q3;
        float dq1 =  wx*q0 + wy*q3 - wz*q2;
        float dq2 =  wy*q0 + wz*q1 - wx*q3;
        float dq3 =  wz*q0 + wx*q2 - wy*q1;
        q0 += dq0; q1 += dq1; q2 += dq2; q3 += dq3;
        float qn2 = sqrtf(q0*q0 + q1*q1 + q2*q2 + q3*q3);
        q0 /= qn2; q1 /= qn2; q2 /= qn2; q3 /= qn2;

        // next plane params
        float qn = sqrtf(q0*q0 + q1*q1 + q2*q2 + q3*q3);
        float w = q0/qn, xq = q1/qn, yq = q2/qn, zq = q3/qn;
        Rm[0] = 1.f - 2.f*yq*yq - 2.f*zq*zq; Rm[1] = 2.f*xq*yq - 2.f*w*zq; Rm[2] = 2.f*xq*zq + 2.f*w*yq;
        Rm[3] = 2.f*xq*yq + 2.f*w*zq; Rm[4] = 1.f - 2.f*xq*xq - 2.f*zq*zq; Rm[5] = 2.f*yq*zq - 2.f*w*xq;
        Rm[6] = 2.f*xq*zq - 2.f*w*yq; Rm[7] = 2.f*yq*zq + 2.f*w*xq; Rm[8] = 1.f - 2.f*xq*xq - 2.f*yq*yq;
        float pl[8];
        pl[0] = Rm[0]*nx + Rm[3]*ny;
        pl[1] = Rm[1]*nx + Rm[4]*ny;
        pl[2] = Rm[2]*nx + Rm[5]*ny;
        float w0 = ny*om2, w1 = -nx*om2, w2 = nx*om1 - ny*om0;
        pl[3] = Rm[0]*w0 + Rm[3]*w1 + Rm[6]*w2;
        pl[4] = Rm[1]*w0 + Rm[4]*w1 + Rm[7]*w2;
        pl[5] = Rm[2]*w0 + Rm[5]*w1 + Rm[8]*w2;
        pl[6] = DTH - ((tr0 + mc0)*nx + (tr1 + mc1)*ny);
        pl[7] = -(v0*nx + v1*ny);

        // broadcast FIRST (critical path): 8 replicas x 8 words
        u64* sl = st + (size_t)((t + 1) & 1) * 64;
        #pragma unroll
        for (int r = 0; r < 8; ++r) {
          #pragma unroll
          for (int k = 0; k < 8; ++k) rec_store(sl + r * 8 + k, rec_pack(pl[k], want));
        }
        // off critical path: own-block handoff, output, hoist next Ii
        #pragma unroll
        for (int k = 0; k < 8; ++k) s_plane[k] = pl[k];
        float* o = out + (size_t)t * 7;
        o[0] = tr0; o[1] = tr1; o[2] = tr2;
        o[3] = q0;  o[4] = q1;  o[5] = q2;  o[6] = q3;
        float Tm[9]; mat3_mul(Rm, In, Tm);
        float Iw[9]; mat3_mul_bt(Tm, Rm, Iw);
        mat3_inv(Iw, Ii);
      }
    }
  } else {
    // =================== NON-LEADER BLOCKS ===================
    const int rep = bid & 7;
    for (int t = 0; t < T; ++t) {
      if (t > 0) {
        if (tid < 8) {
          const u64* sl = st + (size_t)(t & 1) * 64 + (size_t)rep * 8;
          u64 r; int f = 0;
          for (;;) {
            r = rec_load(sl + tid);
            if ((unsigned)(r >> 32) == (unsigned)t) break;
            if ((++f & 31) == 0) __builtin_amdgcn_s_sleep(1);
          }
          s_plane[tid] = __uint_as_float((unsigned)r);
        }
        __syncthreads();
        a0 = s_plane[0]; a1 = s_plane[1]; a2 = s_plane[2];
        b0 = s_plane[3]; b1 = s_plane[4]; b2 = s_plane[5];
        ca = s_plane[6]; cb = s_plane[7];
      }

      float acc[4] = {0.f, 0.f, 0.f, 0.f};
      int i = seg0;
      for (; i + 4 <= segEnd; i += 4) {
        float4 xx = pX4[i >> 2], yy = pY4[i >> 2], zz = pZ4[i >> 2];
        float da, db;
        da = xx.x*a0 + yy.x*a1 + zz.x*a2; db = xx.x*b0 + yy.x*b1 + zz.x*b2;
        if (da < ca && db < cb) { acc[0] += 1.f; acc[1] += xx.x; acc[2] += yy.x; acc[3] += zz.x; }
        da = xx.y*a0 + yy.y*a1 + zz.y*a2; db = xx.y*b0 + yy.y*b1 + zz.y*b2;
        if (da < ca && db < cb) { acc[0] += 1.f; acc[1] += xx.y; acc[2] += yy.y; acc[3] += zz.y; }
        da = xx.z*a0 + yy.z*a1 + zz.z*a2; db = xx.z*b0 + yy.z*b1 + zz.z*b2;
        if (da < ca && db < cb) { acc[0] += 1.f; acc[1] += xx.z; acc[2] += yy.z; acc[3] += zz.z; }
        da = xx.w*a0 + yy.w*a1 + zz.w*a2; db = xx.w*b0 + yy.w*b1 + zz.w*b2;
        if (da < ca && db < cb) { acc[0] += 1.f; acc[1] += xx.w; acc[2] += yy.w; acc[3] += zz.w; }
      }
      for (; i < segEnd; ++i) {
        float x0 = sXx[i], x1 = sXy[i], x2 = sXz[i];
        float da = x0*a0 + x1*a1 + x2*a2;
        float db = x0*b0 + x1*b1 + x2*b2;
        if (da < ca && db < cb) { acc[0] += 1.f; acc[1] += x0; acc[2] += x1; acc[3] += x2; }
      }
      #pragma unroll
      for (int off = 32; off > 0; off >>= 1) {
        #pragma unroll
        for (int k = 0; k < 4; ++k) acc[k] += __shfl_down(acc[k], off, 64);
      }
      if (lane == 0) {
        #pragma unroll
        for (int k = 0; k < 4; ++k) s_red4[wid * 4 + k] = acc[k];
      }
      __syncthreads();
      if (tid == 0) {
        #pragma unroll
        for (int w = 1; w < NWAVES; ++w) {
          #pragma unroll
          for (int k = 0; k < 4; ++k) acc[k] += s_red4[w * 4 + k];
        }
        const unsigned want = (unsigned)(t + 1);
        u64* pb = (t & 1) ? part1 : part0;
        #pragma unroll
        for (int k = 0; k < 4; ++k) rec_store(pb + k * GRID + bid, rec_pack(acc[k], want));
      }
      // WAR safety: a block reaches step t+1's writes only after plane t+1
      // arrived, which the leader sends only after consuming this block's
      // step-t partial.
    }
  }
}

extern "C" void kernel_launch(void* const* d_in, const int* in_sizes, int n_in,
                              void* d_out, int out_size, void* d_ws, size_t ws_size,
                              hipStream_t stream) {
  const float* x   = (const float*)d_in[0];
  const float* mc  = (const float*)d_in[1];
  const float* itr = (const float*)d_in[2];
  const float* iq  = (const float*)d_in[3];
  const float* iv  = (const float*)d_in[4];
  const float* kn  = (const float*)d_in[5];
  const float* mu  = (const float*)d_in[6];
  const float* ldp = (const float*)d_in[7];
  const float* adp = (const float*)d_in[8];
  float* out = (float*)d_out;
  u64* ws  = (u64*)d_ws;
  int N = in_sizes[0] / 3;
  int T = out_size / 7;

  const int dyn_lds = 3 * CHUNKP * 4;   // 93792 B < 160 KB/CU
  hipFuncSetAttribute((const void*)sim_kernel,
                      hipFuncAttributeMaxDynamicSharedMemorySize, dyn_lds);

  void* args[] = {(void*)&x, (void*)&mc, (void*)&itr, (void*)&iq, (void*)&iv,
                  (void*)&kn, (void*)&mu, (void*)&ldp, (void*)&adp,
                  (void*)&out, (void*)&ws, (void*)&N, (void*)&T};
  // cooperative launch kept ONLY for the co-residency guarantee (no grid.sync inside)
  hipLaunchCooperativeKernel((void*)sim_kernel, dim3(GRID), dim3(BLOCK),
                             args, dyn_lds, stream);
}